// Round 13
// baseline (41.855 us; speedup 1.0000x reference)
//
#include <hip/hip_runtime.h>
#include <hip/hip_bf16.h>

// MHSA window attention: B=64 windows, H=32 heads, N=256 tokens, D=16.
// One block per (b,h): 256 threads = 4 waves; wave w handles q-tiles w and w+4
// FUSED in one kv loop: each K/V fragment is ds_read ONCE and feeds both
// q-tiles (24 instead of 48 ds_read_b128/wave), and the two independent
// QK->softmax->PV streams overlap MFMA with VALU naturally.
// mfma_f32_32x32x16_bf16 (K=16 == head_dim). Swapped QK^T -> softmax
// lane-local; P in registers (permlane32_swap); V^T row 16 = ones -> PV
// accumulator reg8 IS the softmax denominator. No __launch_bounds__ (R12:
// removing it lifted a residency cap, -8us). XCD swizzle for L2 pair-locality.

typedef short bf16x8 __attribute__((ext_vector_type(8)));
typedef float f32x16 __attribute__((ext_vector_type(16)));

__device__ __forceinline__ unsigned int pk2(float a, float b) {
  __hip_bfloat162 hh = __float22bfloat162_rn(float2{a, b});   // v_cvt_pk_bf16_f32
  unsigned int u; __builtin_memcpy(&u, &hh, 4); return u;
}

#if __has_builtin(__builtin_amdgcn_permlane32_swap)
typedef int i32x2_t __attribute__((ext_vector_type(2)));
__device__ __forceinline__ void swap_halves(unsigned x, unsigned y, unsigned& ox, unsigned& oy) {
  i32x2_t r = __builtin_amdgcn_permlane32_swap((int)x, (int)y, false, false);
  ox = (unsigned)r.x;
  oy = (unsigned)r.y;
}
#else
__device__ __forceinline__ void swap_halves(unsigned x, unsigned y, unsigned& ox, unsigned& oy) {
  const int hi = (threadIdx.x & 63) >> 5;
  unsigned tx = (unsigned)__shfl_xor((int)x, 32);
  unsigned ty = (unsigned)__shfl_xor((int)y, 32);
  ox = hi ? ty : x;
  oy = hi ? y : tx;
}
#endif

__global__ void mhsa_kernel(const float* __restrict__ inp, const float* __restrict__ table,
                            float* __restrict__ out) {
  const int bid = blockIdx.x;
  const int bh = ((bid & 7) << 8) | (bid >> 3);   // XCD swizzle: pairs share L2
  const int b = bh >> 5, h = bh & 31;
  const int t = threadIdx.x;
  const int l = t & 63;
  const int w = t >> 6;
  const int q32 = l & 31;     // MFMA col (q index)
  const int hi = l >> 5;      // half-wave

  __shared__ __align__(16) short KF[8][64][8];   // K fragment-order: [kv-tile32][lane][8]
  __shared__ __align__(16) short VF[16][34][8];  // V^T frag-order; d=16 row = ones
  __shared__ float tbl[128];                     // bias column * log2(e)

  const float* gbase = inp + (size_t)b * (256 * 1536) + h * 16;
  const int row0 = t >> 2, c4 = t & 3;

  // ---- Issue ALL global loads up front ----
  const float* p0 = gbase + (size_t)(row0      ) * 1536 + c4 * 4;
  const float* p1 = gbase + (size_t)(row0 +  64) * 1536 + c4 * 4;
  const float* p2 = gbase + (size_t)(row0 + 128) * 1536 + c4 * 4;
  const float* p3 = gbase + (size_t)(row0 + 192) * 1536 + c4 * 4;
  float4 ka = *(const float4*)(p0 + 512);
  float4 va = *(const float4*)(p0 + 1024);
  float4 kb_ = *(const float4*)(p1 + 512);
  float4 vb_ = *(const float4*)(p1 + 1024);
  float4 kc = *(const float4*)(p2 + 512);
  float4 vc = *(const float4*)(p2 + 1024);
  float4 kd = *(const float4*)(p3 + 512);
  float4 vd = *(const float4*)(p3 + 1024);
  const float* qp0 = gbase + (size_t)(w * 32 + q32) * 1536 + hi * 8;
  const float* qp1 = qp0 + 4 * 32 * 1536;
  float4 qa0 = *(const float4*)qp0;
  float4 qb0 = *(const float4*)(qp0 + 4);
  float4 qa1 = *(const float4*)qp1;
  float4 qb1 = *(const float4*)(qp1 + 4);

  if (t < 127) tbl[t] = table[t * 32 + h] * 1.4426950408889634f;
  {
    // ones rows (denominator trick): VF[kb][hv*17 + 16][j] = 1.0bf16
    const int kb = t >> 4, hv = (t >> 3) & 1, j = t & 7;
    VF[kb][hv * 17 + 16][j] = (short)0x3F80;
  }

  auto stage = [&](int row, const float4& kv, const float4& vv) {
    short* kdst = &KF[0][0][0] + (row >> 5) * 512 + ((c4 >> 1) * 32 + (row & 31)) * 8 + (c4 & 1) * 4;
    *(int2*)kdst = make_int2(pk2(kv.x, kv.y), pk2(kv.z, kv.w));
    unsigned v01 = pk2(vv.x, vv.y), v23 = pk2(vv.z, vv.w);
    short* vdst = &VF[0][0][0] + (row >> 4) * 272 + (((row >> 3) & 1) * 17 + c4 * 4) * 8 + (row & 7);
    vdst[0]  = (short)(v01 & 0xffff);
    vdst[8]  = (short)(v01 >> 16);
    vdst[16] = (short)(v23 & 0xffff);
    vdst[24] = (short)(v23 >> 16);
  };
  stage(row0, ka, va);
  stage(row0 + 64, kb_, vb_);
  stage(row0 + 128, kc, vc);
  stage(row0 + 192, kd, vd);

  // Q -> bf16 B-frags for both tiles
  bf16x8 q8A, q8B;
  { unsigned qw[4] = { pk2(qa0.x, qa0.y), pk2(qa0.z, qa0.w),
                       pk2(qb0.x, qb0.y), pk2(qb0.z, qb0.w) };
    __builtin_memcpy(&q8A, qw, 16); }
  { unsigned qw[4] = { pk2(qa1.x, qa1.y), pk2(qa1.z, qa1.w),
                       pk2(qb1.x, qb1.y), pk2(qb1.z, qb1.w) };
    __builtin_memcpy(&q8B, qw, 16); }

  __syncthreads();

  const float scale2 = 0.17677669529663687f * 1.4426950408889634f;  // 32^-0.5 * log2e
  const f32x16 z16 = {0.f};
  const short* kfb = &KF[0][0][0] + l * 8;                       // linear: conflict-free
  const int vslot = hi * 17 + (q32 > 16 ? 16 : q32);             // d row (>=16 -> ones row)
  const short* vfb = &VF[0][0][0] + vslot * 8;

  const int qbaseA = w * 32;
  const int qbaseB = (w + 4) * 32;
  const int bbA = (qbaseA >> 2) + (q32 >> 2) + 63 - hi;
  const int bbB = (qbaseB >> 2) + (q32 >> 2) + 63 - hi;

  // softmax + PV body for one 32kv tile (kt), consuming S-tile `s`
  auto body = [&](int kt, const f32x16& s, const bf16x8& v0, const bf16x8& v1,
                  f32x16& o, int bb) {
    unsigned wd[8];
    #pragma unroll
    for (int m = 0; m < 4; ++m) {
      const float bias = tbl[bb - kt * 8 - 2 * m];
      float e0 = __builtin_amdgcn_exp2f(fmaf(s[4 * m + 0], scale2, bias));
      float e1 = __builtin_amdgcn_exp2f(fmaf(s[4 * m + 1], scale2, bias));
      float e2 = __builtin_amdgcn_exp2f(fmaf(s[4 * m + 2], scale2, bias));
      float e3 = __builtin_amdgcn_exp2f(fmaf(s[4 * m + 3], scale2, bias));
      wd[2 * m]     = pk2(e0, e1);
      wd[2 * m + 1] = pk2(e2, e3);
    }
    unsigned f0, f1, f2, f3;
    bf16x8 pf0, pf1;
    swap_halves(wd[0], wd[2], f0, f2);
    swap_halves(wd[1], wd[3], f1, f3);
    { unsigned a4[4] = { f0, f1, f2, f3 }; __builtin_memcpy(&pf0, a4, 16); }
    swap_halves(wd[4], wd[6], f0, f2);
    swap_halves(wd[5], wd[7], f1, f3);
    { unsigned a4[4] = { f0, f1, f2, f3 }; __builtin_memcpy(&pf1, a4, 16); }
    o = __builtin_amdgcn_mfma_f32_32x32x16_bf16(v0, pf0, o, 0, 0, 0);
    o = __builtin_amdgcn_mfma_f32_32x32x16_bf16(v1, pf1, o, 0, 0, 0);
  };

  f32x16 oA = z16, oB = z16;

  #pragma unroll 2
  for (int kt = 0; kt < 8; ++kt) {
    bf16x8 kf = *(const bf16x8*)(kfb + kt * 512);
    bf16x8 v0 = *(const bf16x8*)(vfb + (kt * 2 + 0) * 272);
    bf16x8 v1 = *(const bf16x8*)(vfb + (kt * 2 + 1) * 272);
    f32x16 sA = __builtin_amdgcn_mfma_f32_32x32x16_bf16(kf, q8A, z16, 0, 0, 0);
    f32x16 sB = __builtin_amdgcn_mfma_f32_32x32x16_bf16(kf, q8B, z16, 0, 0, 0);
    body(kt, sA, v0, v1, oA, bbA);   // sB's MFMA in flight under A's exp chain
    body(kt, sB, v0, v1, oB, bbB);   // A's PV MFMAs retire under B's VALU
  }

  // denominator: C row16 = reg8 of hi=0 lanes; broadcast to both halves
  {
    const float inv = 1.0f / __shfl(oA[8], q32);
    float* op = out + (size_t)(b * 256 + qbaseA + q32) * 512 + h * 16 + hi * 4;
    float4 r0 = { oA[0] * inv, oA[1] * inv, oA[2] * inv, oA[3] * inv };
    float4 r1 = { oA[4] * inv, oA[5] * inv, oA[6] * inv, oA[7] * inv };
    *(float4*)op = r0;
    *(float4*)(op + 8) = r1;
  }
  {
    const float inv = 1.0f / __shfl(oB[8], q32);
    float* op = out + (size_t)(b * 256 + qbaseB + q32) * 512 + h * 16 + hi * 4;
    float4 r0 = { oB[0] * inv, oB[1] * inv, oB[2] * inv, oB[3] * inv };
    float4 r1 = { oB[4] * inv, oB[5] * inv, oB[6] * inv, oB[7] * inv };
    *(float4*)op = r0;
    *(float4*)(op + 8) = r1;
  }
}

extern "C" void kernel_launch(void* const* d_in, const int* in_sizes, int n_in,
                              void* d_out, int out_size, void* d_ws, size_t ws_size,
                              hipStream_t stream) {
  (void)in_sizes; (void)n_in; (void)out_size; (void)d_ws; (void)ws_size;
  const float* inp = (const float*)d_in[0];
  const float* tbl = (const float*)d_in[1];
  float* out = (float*)d_out;
  hipLaunchKernelGGL(mhsa_kernel, dim3(2048), dim3(256), 0, stream, inp, tbl, out);
}

// Round 14
// 36.029 us; speedup vs baseline: 1.1617x; 1.1617x over previous
//
#include <hip/hip_runtime.h>
#include <hip/hip_bf16.h>

// MHSA window attention: B=64 windows, H=32 heads, N=256 tokens, D=16.
// One block per (b,h): 512 threads = 8 waves; wave w owns q-tile w (32 q rows).
// 2048 blocks -> 4 blocks/CU x 8 waves = 32 waves/CU (full occupancy packing);
// per-wave serial work halved vs the 4-wave/2-tile variant.
// mfma_f32_32x32x16_bf16 (K=16 == head_dim). Swapped QK^T -> softmax
// lane-local; P in registers (permlane32_swap); V^T row 16 = ones -> PV
// accumulator reg8 IS the softmax denominator. QK pipelined 1 kt ahead.
// No __launch_bounds__ (R12: the hint capped residency). XCD swizzle for L2.

typedef short bf16x8 __attribute__((ext_vector_type(8)));
typedef float f32x16 __attribute__((ext_vector_type(16)));

__device__ __forceinline__ unsigned int pk2(float a, float b) {
  __hip_bfloat162 hh = __float22bfloat162_rn(float2{a, b});   // v_cvt_pk_bf16_f32
  unsigned int u; __builtin_memcpy(&u, &hh, 4); return u;
}

#if __has_builtin(__builtin_amdgcn_permlane32_swap)
typedef int i32x2_t __attribute__((ext_vector_type(2)));
__device__ __forceinline__ void swap_halves(unsigned x, unsigned y, unsigned& ox, unsigned& oy) {
  i32x2_t r = __builtin_amdgcn_permlane32_swap((int)x, (int)y, false, false);
  ox = (unsigned)r.x;
  oy = (unsigned)r.y;
}
#else
__device__ __forceinline__ void swap_halves(unsigned x, unsigned y, unsigned& ox, unsigned& oy) {
  const int hi = (threadIdx.x & 63) >> 5;
  unsigned tx = (unsigned)__shfl_xor((int)x, 32);
  unsigned ty = (unsigned)__shfl_xor((int)y, 32);
  ox = hi ? ty : x;
  oy = hi ? y : tx;
}
#endif

__global__ void mhsa_kernel(const float* __restrict__ inp, const float* __restrict__ table,
                            float* __restrict__ out) {
  const int bid = blockIdx.x;
  const int bh = ((bid & 7) << 8) | (bid >> 3);   // XCD swizzle: neighbors share L2
  const int b = bh >> 5, h = bh & 31;
  const int t = threadIdx.x;
  const int l = t & 63;
  const int w = t >> 6;       // wave 0..7 -> q-tile w
  const int q32 = l & 31;     // MFMA col (q index)
  const int hi = l >> 5;      // half-wave

  __shared__ __align__(16) short KF[8][64][8];   // K fragment-order: [kv-tile32][lane][8]
  __shared__ __align__(16) short VF[16][34][8];  // V^T frag-order; d=16 row = ones
  __shared__ float tbl[128];                     // bias column * log2(e)

  const float* gbase = inp + (size_t)b * (256 * 1536) + h * 16;
  const int row0 = t >> 2, c4 = t & 3;           // rows 0..127 (+128)

  // ---- Issue all global loads up front ----
  const float* p0 = gbase + (size_t)row0 * 1536 + c4 * 4;
  const float* p1 = gbase + (size_t)(row0 + 128) * 1536 + c4 * 4;
  float4 ka = *(const float4*)(p0 + 512);
  float4 va = *(const float4*)(p0 + 1024);
  float4 kb_ = *(const float4*)(p1 + 512);
  float4 vb_ = *(const float4*)(p1 + 1024);
  const float* qp = gbase + (size_t)(w * 32 + q32) * 1536 + hi * 8;
  float4 qa = *(const float4*)qp;
  float4 qb = *(const float4*)(qp + 4);

  if (t < 127) tbl[t] = table[t * 32 + h] * 1.4426950408889634f;
  if (t < 256) {
    // ones rows (denominator trick): VF[kb][hv*17 + 16][j] = 1.0bf16
    const int kb = t >> 4, hv = (t >> 3) & 1, j = t & 7;
    VF[kb][hv * 17 + 16][j] = (short)0x3F80;
  }

  auto stage = [&](int row, const float4& kv, const float4& vv) {
    short* kdst = &KF[0][0][0] + (row >> 5) * 512 + ((c4 >> 1) * 32 + (row & 31)) * 8 + (c4 & 1) * 4;
    *(int2*)kdst = make_int2(pk2(kv.x, kv.y), pk2(kv.z, kv.w));
    unsigned v01 = pk2(vv.x, vv.y), v23 = pk2(vv.z, vv.w);
    short* vdst = &VF[0][0][0] + (row >> 4) * 272 + (((row >> 3) & 1) * 17 + c4 * 4) * 8 + (row & 7);
    vdst[0]  = (short)(v01 & 0xffff);
    vdst[8]  = (short)(v01 >> 16);
    vdst[16] = (short)(v23 & 0xffff);
    vdst[24] = (short)(v23 >> 16);
  };
  stage(row0, ka, va);
  stage(row0 + 128, kb_, vb_);

  // Q -> bf16 B-frag for this wave's tile
  bf16x8 q8;
  { unsigned qw[4] = { pk2(qa.x, qa.y), pk2(qa.z, qa.w),
                       pk2(qb.x, qb.y), pk2(qb.z, qb.w) };
    __builtin_memcpy(&q8, qw, 16); }

  __syncthreads();

  const float scale2 = 0.17677669529663687f * 1.4426950408889634f;  // 32^-0.5 * log2e
  const f32x16 z16 = {0.f};
  const short* kfb = &KF[0][0][0] + l * 8;                       // linear: conflict-free
  const int vslot = hi * 17 + (q32 > 16 ? 16 : q32);             // d row (>=16 -> ones row)
  const short* vfb = &VF[0][0][0] + vslot * 8;

  const int qbase = w * 32;
  const int bb = (qbase >> 2) + (q32 >> 2) + 63 - hi;

  // softmax + PV body for one 32kv tile (kt), consuming S-tile `s`
  auto body = [&](int kt, const f32x16& s, f32x16& o) {
    unsigned wd[8];
    #pragma unroll
    for (int m = 0; m < 4; ++m) {
      const float bias = tbl[bb - kt * 8 - 2 * m];
      float e0 = __builtin_amdgcn_exp2f(fmaf(s[4 * m + 0], scale2, bias));
      float e1 = __builtin_amdgcn_exp2f(fmaf(s[4 * m + 1], scale2, bias));
      float e2 = __builtin_amdgcn_exp2f(fmaf(s[4 * m + 2], scale2, bias));
      float e3 = __builtin_amdgcn_exp2f(fmaf(s[4 * m + 3], scale2, bias));
      wd[2 * m]     = pk2(e0, e1);
      wd[2 * m + 1] = pk2(e2, e3);
    }
    unsigned f0, f1, f2, f3;
    bf16x8 pf0, pf1;
    swap_halves(wd[0], wd[2], f0, f2);
    swap_halves(wd[1], wd[3], f1, f3);
    { unsigned a4[4] = { f0, f1, f2, f3 }; __builtin_memcpy(&pf0, a4, 16); }
    swap_halves(wd[4], wd[6], f0, f2);
    swap_halves(wd[5], wd[7], f1, f3);
    { unsigned a4[4] = { f0, f1, f2, f3 }; __builtin_memcpy(&pf1, a4, 16); }
    bf16x8 v0 = *(const bf16x8*)(vfb + (kt * 2 + 0) * 272);
    bf16x8 v1 = *(const bf16x8*)(vfb + (kt * 2 + 1) * 272);
    o = __builtin_amdgcn_mfma_f32_32x32x16_bf16(v0, pf0, o, 0, 0, 0);
    o = __builtin_amdgcn_mfma_f32_32x32x16_bf16(v1, pf1, o, 0, 0, 0);
  };

  // QK software-pipelined one kt ahead
  f32x16 o = z16;
  {
    bf16x8 kf0 = *(const bf16x8*)kfb;
    f32x16 s = __builtin_amdgcn_mfma_f32_32x32x16_bf16(kf0, q8, z16, 0, 0, 0);
    #pragma unroll
    for (int kt = 0; kt < 7; ++kt) {
      bf16x8 kfn = *(const bf16x8*)(kfb + (kt + 1) * 512);
      f32x16 s_next = __builtin_amdgcn_mfma_f32_32x32x16_bf16(kfn, q8, z16, 0, 0, 0);
      body(kt, s, o);
      s = s_next;
    }
    body(7, s, o);
  }

  // denominator: C row16 = reg8 of hi=0 lanes; broadcast to both halves
  const float inv = 1.0f / __shfl(o[8], q32);
  float* op = out + (size_t)(b * 256 + qbase + q32) * 512 + h * 16 + hi * 4;
  float4 r0 = { o[0] * inv, o[1] * inv, o[2] * inv, o[3] * inv };
  float4 r1 = { o[4] * inv, o[5] * inv, o[6] * inv, o[7] * inv };
  *(float4*)op = r0;
  *(float4*)(op + 8) = r1;
}

extern "C" void kernel_launch(void* const* d_in, const int* in_sizes, int n_in,
                              void* d_out, int out_size, void* d_ws, size_t ws_size,
                              hipStream_t stream) {
  (void)in_sizes; (void)n_in; (void)out_size; (void)d_ws; (void)ws_size;
  const float* inp = (const float*)d_in[0];
  const float* tbl = (const float*)d_in[1];
  float* out = (float*)d_out;
  hipLaunchKernelGGL(mhsa_kernel, dim3(2048), dim3(512), 0, stream, inp, tbl, out);
}